// Round 7
// baseline (212.384 us; speedup 1.0000x reference)
//
#include <hip/hip_runtime.h>

// Boosted neural LDPC min-sum decoder, MI355X.
// R14: plain stream-ordered launches (capture-safe), 10 dispatches.
// Key change vs R13 (172.6us): k_fit processes 4 z PER THREAD with dword-wide
// memory ops. R13's k_fit (~15us) was VMEM-ISSUE bound: ~84 VMEM instrs per
// check-z (56 padded byte-gathers + 7 llr + 7 own + 14 byte stores). Now:
//  - gathers: 2 aligned dword loads + 64-bit funnel shift per 4z (alignment-
//    safe for arbitrary circulant shifts; halo'd planes absorb the +7B overrun)
//  - exact-dv loops (no 8-slot padding; dv is wave-uniform per 96-group)
//  - own-message read / msg stores: single aligned dwords (zb%4==0)
//  - per-block tables staged in LDS (handles 96-thread check groups crossing
//    wave boundaries without per-lane global table reads)
//  => ~29 VMEM per check-z (2.9x cut). Grid 384x384 (4 checks/block).
// R13 lessons kept: parallel table build; halo'd (2Z) planes; XCD swizzle.
// R10 lesson: persistent spin-barrier kernels deadlock under harness - banned.
// Sizes fixed by setup_inputs(): B=32, Z=384, N=68, M=46, dc=7, E=322, iters=8.
#define B_   32
#define Z_   384
#define N_   68
#define M_   46
#define DC_  7
#define E_   (M_ * DC_)      // 322
#define ZN   (Z_ * N_)       // 26112
#define ZM   (Z_ * M_)       // 17664
#define Z2   768             // halo'd plane length (2*Z)
#define MAXDV 20             // max variable degree supported (avg 4.7)

// halo'd message layout: [b][j][m][Z2] bytes + per-batch zero tail
#define PLZ(j,m) (((j) * M_ + (m)) * Z2)     // byte offset within batch
#define ZT    (DC_ * M_ * Z2)                // 247296 = zero-tail start (k_out dummies)
#define MS2S  (ZT + 1152)                    // per-batch msg bytes (div by 4)
// per-check gather table (ints):
//  [0..6]    llr base (vn*Z2 + s_j)        -> addr = xat2 + base + z
//  [7..13]   dv_j (exact)
//  [14+j*20+q] dv_j msg slot bases (byte offs, combined shift pre-added)
#define CST3  154
// per-variable out table: [0..7] recs (ZT dummies), [8]=dvx, [9..20] ext
#define OST   21

// ---- workspace layout (int32 offsets) ----
#define W2_XAT  0                            // float xat2[B][N][Z2]
#define XAT2I   (B_ * N_ * Z2)
#define MS2I    (B_ * MS2S / 4)
#define W2_MSG0 (W2_XAT + XAT2I)             // sbyte msg0[B][MS2S]
#define W2_MSG1 (W2_MSG0 + MS2I)             // sbyte msg1[B][MS2S]
#define W2_CHK  (W2_MSG1 + MS2I)             // int chk[M][CST3]
#define W2_OUT  (W2_CHK + M_ * CST3)         // int outt[N][OST]
#define W2_END  (W2_OUT + N_ * OST)          // ~5.65M ints ~= 22.6 MB

// msg[b][j][m][z(+Z)] = c2v message on edge j of check (m,z), sign applied, in
// half-steps, range [-15,15]. Exact ints -> fp arithmetic identical to JAX ref.

// ==================== k_pre: transpose(+halo) + PARALLEL tables ====================
// Blocks 0..191: xat2[b][n][z]=xat2[b][n][z+Z]=xa[b][z][n]; also zero a slice
// of both msg tails for batch b (k_out dummy target). Block 192: tables.
__global__ __launch_bounds__(384)
void k_pre(const float* __restrict__ xa,
           const int* __restrict__ vn_idx, const int* __restrict__ shifts,
           int* __restrict__ ws)
{
    const int tid = threadIdx.x;
    if (blockIdx.x == B_ * 6) {
        // ---- parallel table build (1 block); list order is arbitrary:
        //      sums of exact ints are order-free, so atomics are safe. ----
        __shared__ int vnl[E_], shl[E_], cntS[N_], posS[N_], offsS[N_ + 1], lstS[E_];
        if (tid < E_) { vnl[tid] = vn_idx[tid]; shl[tid] = shifts[tid]; }
        if (tid < N_) { cntS[tid] = 0; posS[tid] = 0; }
        __syncthreads();
        if (tid < E_) atomicAdd(&cntS[vnl[tid]], 1);
        __syncthreads();
        if (tid == 0) {
            offsS[0] = 0;
            for (int n = 0; n < N_; ++n) offsS[n + 1] = offsS[n] + cntS[n];
        }
        __syncthreads();
        if (tid < E_) {
            int m = tid / DC_, j = tid - m * DC_;
            int vn = vnl[tid];
            int r = atomicAdd(&posS[vn], 1);
            lstS[offsS[vn] + r] = (PLZ(j, m) << 9) | shl[tid];   // plane off | s'
        }
        __syncthreads();
        if (tid < E_) {             // per-check gather table (parallel per edge)
            int m = tid / DC_, j = tid - m * DC_;
            int vn = vnl[tid], sj = shl[tid];
            int* rec = ws + W2_CHK + m * CST3;
            rec[j] = vn * Z2 + sj;                        // llr base
            int o = offsS[vn];
            int dv = cntS[vn]; if (dv > MAXDV) dv = MAXDV;
            rec[7 + j] = dv;                              // exact count
            for (int q = 0; q < dv; ++q) {
                int lr = lstS[o + q];
                int sc = sj - (lr & 511); if (sc < 0) sc += Z_;  // combined shift
                rec[14 + j * 20 + q] = (lr >> 9) + sc;    // slot base (byte off)
            }
        }
        if (tid < N_) {             // per-variable out table (k_out, 8-padded)
            int* rr = ws + W2_OUT + tid * OST;
            int o = offsS[tid];
            int dv = cntS[tid]; if (dv > MAXDV) dv = MAXDV;
            rr[8] = (dv > 8) ? dv - 8 : 0;
            for (int q = 0; q < 8; ++q) {
                int slot = ZT;
                if (q < dv) { int lr = lstS[o + q]; slot = (lr >> 9) + (Z_ - (lr & 511)); }
                rr[q] = slot;                             // addr = base + z (halo'd)
            }
            for (int q = 8; q < dv; ++q) {
                int lr = lstS[o + q];
                rr[9 + (q - 8)] = (lr >> 9) + (Z_ - (lr & 511));
            }
        }
        return;
    }
    // ---- transpose: block = swizzled (b, 64-z tile); halo'd stores ----
    __shared__ float tile[N_ * 65];           // [n][zl], pad 65 breaks conflicts
    const int x = blockIdx.x & 7;
    const int k = blockIdx.x >> 3;            // 0..23
    const int b = x + 8 * (k & 3);            // b % 8 == x -> XCD locality
    const int t = k >> 2;                     // 0..5
    const int z0 = t * 64;
    const float* src = xa + (size_t)b * ZN + (size_t)z0 * N_;
    for (int i = tid; i < 64 * N_; i += 384) {  // contiguous 17 KB read
        int r = i / N_, n = i - r * N_;
        tile[n * 65 + r] = src[i];
    }
    // zero msg tails (k_out dummy target), slice t of batch b, both buffers
    {
        int* t0 = ws + W2_MSG0 + (b * MS2S + ZT) / 4;
        int* t1 = ws + W2_MSG1 + (b * MS2S + ZT) / 4;
        if (tid < 48) t0[t * 48 + tid] = 0;
        else if (tid < 96) t1[t * 48 + (tid - 48)] = 0;
    }
    __syncthreads();
    float* dst = (float*)(ws + W2_XAT) + (size_t)b * N_ * Z2;
    for (int i = tid; i < 64 * N_; i += 384) {
        int n = i >> 6, zl = i & 63;
        float v = tile[n * 65 + zl];
        dst[n * Z2 + z0 + zl] = v;            // main copy
        dst[n * Z2 + z0 + zl + Z_] = v;       // halo copy
    }
}

// ==================== k_fit: fused iteration, 4 z per thread ====================
// Grid B_*12 = 384 blocks x 384 threads. Thread = (check m, 4-z group) of
// batch b: c = tid/96 (check in block), zb = 4*(tid%96). All msg traffic is
// dword-wide; gathers use 2 aligned dwords + 64-bit funnel shift (the halo'd
// plane absorbs the <=7B over-read: max touched byte = plane+767 < Z2).
template <bool INIT>
__global__ __launch_bounds__(384)
void k_fit(const float* __restrict__ cw, const int* __restrict__ ws,
           const signed char* __restrict__ mold, signed char* __restrict__ mnew,
           int it)
{
    __shared__ int tbl[4 * CST3];
    const int tid = threadIdx.x;
    const int bid = blockIdx.x;
    const int b = (bid & 7) + 8 * ((bid >> 3) & 3);   // b % 8 == bid % 8 (XCD)
    const int tile = bid >> 5;                // 0..11
    for (int i = tid; i < 4 * CST3; i += 384) {
        int mm = tile * 4 + i / CST3;
        if (mm < M_) tbl[i] = ws[W2_CHK + mm * CST3 + (i - (i / CST3) * CST3)];
    }
    __syncthreads();
    const int c = tid / 96;
    const int g = tid - 96 * c;
    const int m = tile * 4 + c;
    if (m >= M_) return;                      // tile 11: checks 46,47 idle
    const int zb = 4 * g;
    const int* tb = &tbl[c * CST3];
    const float* xb = (const float*)(ws + W2_XAT) + (size_t)b * N_ * Z2;
    const unsigned* mo4 = (const unsigned*)(mold + (size_t)b * MS2S);
    unsigned* mn4 = (unsigned*)(mnew + (size_t)b * MS2S);
    const float w = cw[it];

    float m1[4], m2[4];
    int f[4], ng[4];
    #pragma unroll
    for (int k = 0; k < 4; ++k) { m1[k] = 1e30f; m2[k] = 1e30f; f[k] = 0; ng[k] = 0; }

    #pragma unroll
    for (int j = 0; j < DC_; ++j) {
        const int lb = tb[j] + zb;
        float vv[4];
        #pragma unroll
        for (int k = 0; k < 4; ++k) vv[k] = xb[lb + k];   // llr_e (halo'd xat)
        if (!INIT) {
            int t2[4] = {0, 0, 0, 0};
            const int dv = tb[7 + j];                      // uniform per 96-group
            for (int q = 0; q < dv; ++q) {
                const int a = tb[14 + j * 20 + q] + zb;    // byte addr in batch msg
                const int a0 = a >> 2;                     // aligned dword index
                const int r = (a & 3) * 8;
                unsigned w0 = mo4[a0], w1 = mo4[a0 + 1];
                unsigned long long dw = ((unsigned long long)w1 << 32) | w0;
                unsigned packed = (unsigned)(dw >> r);     // bytes a..a+3
                #pragma unroll
                for (int k = 0; k < 4; ++k)
                    t2[k] += (int)(signed char)(packed >> (8 * k));
            }
            const unsigned ow = mo4[(PLZ(j, m) + zb) >> 2];   // own old messages
            #pragma unroll
            for (int k = 0; k < 4; ++k) {
                int c2 = (int)(signed char)(ow >> (8 * k));
                // identical roundings to ref: fl(fl(llr + tot) - c2v)
                float lt = vv[k] + 0.5f * (float)t2[k];
                vv[k] = lt - 0.5f * (float)c2;
            }
        }
        #pragma unroll
        for (int k = 0; k < 4; ++k) {
            float v = fminf(fmaxf(vv[k], -20.0f), 20.0f);
            ng[k] |= (v < 0.0f) << j;
            float a = fabsf(v);
            if (a < m1[k]) { m2[k] = m1[k]; m1[k] = a; f[k] = j; }
            else if (a < m2[k]) { m2[k] = a; }
        }
    }
    // quantize-STE forward: clip(rint(2*w*min)/2, +-7.5), as int half-steps
    int q1[4], q2[4], par[4];
    #pragma unroll
    for (int k = 0; k < 4; ++k) {
        float r1 = fminf(fmaxf(rintf(w * m1[k] * 2.0f), -15.0f), 15.0f);
        float r2 = fminf(fmaxf(rintf(w * m2[k] * 2.0f), -15.0f), 15.0f);
        q1[k] = (int)r1; q2[k] = (int)r2; par[k] = __popc(ng[k]);
    }
    #pragma unroll
    for (int j = 0; j < DC_; ++j) {
        unsigned outw = 0;
        #pragma unroll
        for (int k = 0; k < 4; ++k) {
            int q = (j == f[k]) ? q2[k] : q1[k];
            int sj = (par[k] - ((ng[k] >> j) & 1)) & 1;   // parity of other edges
            outw |= ((unsigned)((sj ? -q : q) & 0xff)) << (8 * k);
        }
        const int base = PLZ(j, m) + zb;
        mn4[base >> 2] = outw;                 // main copy (aligned dword)
        mn4[(base + Z_) >> 2] = outw;          // halo copy (Z%4==0 -> aligned)
    }
}

// ==================== k_out: final variable totals ====================
// Grid 1088 blocks x 384 threads (2 variables/block).
__global__ __launch_bounds__(384)
void k_out(const int* __restrict__ ws, const signed char* __restrict__ msg,
           float* __restrict__ dst)
{
    const int tid = threadIdx.x;
    const int bid = blockIdx.x;
    const int b = (bid & 7) + 8 * ((bid >> 3) & 3);
    const int kk = bid >> 5;                  // 0..33
    const int z = tid;
    const signed char* mb = msg + (size_t)b * MS2S;
    const float* xb = (const float*)(ws + W2_XAT) + (size_t)b * N_ * Z2;
    for (int s = 0; s < 2; ++s) {
        const int n = 2 * kk + s;
        const int* rr = ws + W2_OUT + n * OST;        // uniform -> scalar loads
        int t2 = 0;
        #pragma unroll
        for (int q = 0; q < 8; ++q)
            t2 += (int)mb[rr[q] + z];
        const int dvx = rr[8];
        for (int q = 0; q < dvx; ++q)
            t2 += (int)mb[rr[9 + q] + z];
        // fl(llr + tot); dst layout == out layout [b][n*Z+z]
        dst[(size_t)b * ZN + n * Z_ + z] = xb[n * Z2 + z] + 0.5f * (float)t2;
    }
}

// ==================== k_tr: iters==0 -> out = transpose(xa) ====================
__global__ __launch_bounds__(384)
void k_tr(const float* __restrict__ xa, float* __restrict__ dst_g)
{
    __shared__ float tile[N_ * 65];
    const int tid = threadIdx.x;
    const int x = blockIdx.x & 7;
    const int k = blockIdx.x >> 3;
    const int b = x + 8 * (k & 3);
    const int t = k >> 2;
    const int z0 = t * 64;
    const float* src = xa + (size_t)b * ZN + (size_t)z0 * N_;
    for (int i = tid; i < 64 * N_; i += 384) {
        int r = i / N_, n = i - r * N_;
        tile[n * 65 + r] = src[i];
    }
    __syncthreads();
    float* dst = dst_g + (size_t)b * ZN + z0;
    for (int i = tid; i < 64 * N_; i += 384) {
        int n = i >> 6, zl = i & 63;
        dst[n * Z_ + zl] = tile[n * 65 + zl];
    }
}

// ==================== fallback: single-block-per-batch kernel (small ws) ====================
#define INIT_STATE ((16u << 10) | (16u << 15))
__device__ __forceinline__ int decode2(unsigned st, int j) {
    int neg   = (st >> j) & 1;
    int q1    = (int)((st >> 10) & 31) - 16;
    int q2    = (int)((st >> 15) & 31) - 16;
    int first = (int)((st >> 7) & 7);
    int q     = (j == first) ? q2 : q1;
    int par   = (__popc(st & 127u) - neg) & 1;
    return par ? -q : q;
}

__global__ __launch_bounds__(1024)
void ldpc_decode_kernel(const float* __restrict__ xa,
                        const float* __restrict__ cw,
                        const int*   __restrict__ vn_idx,
                        const int*   __restrict__ shifts,
                        float* out, int iters)
{
    __shared__ short tot[ZN];
    __shared__ int   evs[E_];
    __shared__ int   offs[N_ + 1];
    __shared__ int   lists[E_];
    __shared__ float wlds[8];

    const int tid = threadIdx.x;
    const int b   = blockIdx.x;
    const float* xab = xa + (size_t)b * ZN;
    float* outb = out + (size_t)b * ZN;
    int* stateg = (int*)outb;

    if (tid < E_) evs[tid] = vn_idx[tid] | (shifts[tid] << 7);
    if (tid < iters && tid < 8) wlds[tid] = cw[tid];
    __syncthreads();
    if (tid < N_) {
        int c = 0;
        for (int e = 0; e < E_; ++e) c += ((evs[e] & 127) == tid);
        offs[tid + 1] = c;
    }
    if (tid == 0) offs[0] = 0;
    __syncthreads();
    if (tid == 0) { for (int n = 0; n < N_; ++n) offs[n + 1] += offs[n]; }
    __syncthreads();
    if (tid < N_) {
        int p = offs[tid];
        for (int e = 0; e < E_; ++e) {
            int rec = evs[e];
            if ((rec & 127) == tid) {
                int s = rec >> 7;
                lists[p++] = s | ((e / DC_) << 9) | ((e % DC_) << 15);
            }
        }
    }
    __syncthreads();

    for (int i = tid; i < ZM; i += 1024) stateg[i] = (int)INIT_STATE;
    __syncthreads();

    for (int it = 0; it < iters; ++it) {
        for (int i = tid; i < ZN; i += 1024) {
            int z = i / N_, n = i - z * N_, t2 = 0;
            int kend = offs[n + 1];
            for (int k = offs[n]; k < kend; ++k) {
                int rec = lists[k];
                int s = rec & 511, m = (rec >> 9) & 63, j = rec >> 15;
                int zs = z - s; if (zs < 0) zs += Z_;
                t2 += decode2((unsigned)stateg[zs * M_ + m], j);
            }
            tot[i] = (short)t2;
        }
        __syncthreads();
        const float w = wlds[it];
        for (int i = tid; i < ZM; i += 1024) {
            int z = i / M_, m = i - z * M_;
            unsigned st = (unsigned)stateg[i];
            float m1 = 1e30f, m2 = 1e30f;
            int f = 0, negb = 0;
            #pragma unroll
            for (int j = 0; j < DC_; ++j) {
                int rec = evs[m * DC_ + j];
                int vn = rec & 127, s = rec >> 7;
                int zr = z + s; if (zr >= Z_) zr -= Z_;
                int c2 = decode2(st, j);
                int idx = zr * N_ + vn;
                float v = (xab[idx] + 0.5f * (float)tot[idx]) - 0.5f * (float)c2;
                v = fminf(fmaxf(v, -20.0f), 20.0f);
                negb |= (v < 0.0f) << j;
                float a = fabsf(v);
                if (a < m1) { m2 = m1; m1 = a; f = j; }
                else if (a < m2) { m2 = a; }
            }
            float r1 = fminf(fmaxf(rintf(w * m1 * 2.0f), -15.0f), 15.0f);
            float r2 = fminf(fmaxf(rintf(w * m2 * 2.0f), -15.0f), 15.0f);
            stateg[i] = (int)(unsigned)(negb | (f << 7) | (((int)r1 + 16) << 10) | (((int)r2 + 16) << 15));
        }
        __syncthreads();
    }

    for (int i = tid; i < ZN; i += 1024) {
        int z = i / N_, n = i - z * N_, t2 = 0;
        int kend = offs[n + 1];
        for (int k = offs[n]; k < kend; ++k) {
            int rec = lists[k];
            int s = rec & 511, m = (rec >> 9) & 63, j = rec >> 15;
            int zs = z - s; if (zs < 0) zs += Z_;
            t2 += decode2((unsigned)stateg[zs * M_ + m], j);
        }
        tot[i] = (short)t2;
    }
    __syncthreads();
    for (int i = tid; i < ZN; i += 1024) {
        int n = i / Z_, z = i - n * Z_;
        outb[i] = xab[z * N_ + n] + 0.5f * (float)tot[z * N_ + n];
    }
}

extern "C" void kernel_launch(void* const* d_in, const int* in_sizes, int n_in,
                              void* d_out, int out_size, void* d_ws, size_t ws_size,
                              hipStream_t stream) {
    const float* xa = (const float*)d_in[0];
    const float* cw = (const float*)d_in[1];
    const int* vn   = (const int*)d_in[2];
    // d_in[3] = cn_idx: repeat(arange(M), dc) by construction — implicit.
    const int* sh   = (const int*)d_in[4];
    int iters = in_sizes[1];
    float* outp = (float*)d_out;

    if (ws_size >= (size_t)W2_END * sizeof(int)) {
        int*         ws   = (int*)d_ws;
        signed char* msg0 = (signed char*)(ws + W2_MSG0);
        signed char* msg1 = (signed char*)(ws + W2_MSG1);

        if (iters == 0) {   // out = transpose(xa)
            hipLaunchKernelGGL(k_tr, dim3(B_ * 6), dim3(384), 0, stream, xa, outp);
            return;
        }
        // transpose(+halo) + parallel tables + tail zeroing
        hipLaunchKernelGGL(k_pre, dim3(B_ * 6 + 1), dim3(384), 0, stream,
                           xa, vn, sh, ws);
        // it = 0: v = clip(llr) only, writes msg0
        hipLaunchKernelGGL((k_fit<true>), dim3(B_ * 12), dim3(384), 0, stream,
                           cw, ws, msg0, msg0, 0);
        // it = 1..iters-1: fused variable-total + check update, ping-pong
        for (int it = 1; it < iters; ++it) {
            signed char* wbuf = (it & 1) ? msg1 : msg0;
            signed char* rbuf = (it & 1) ? msg0 : msg1;
            hipLaunchKernelGGL((k_fit<false>), dim3(B_ * 12), dim3(384), 0, stream,
                               cw, ws, rbuf, wbuf, it);
        }
        signed char* fin = ((iters - 1) & 1) ? msg1 : msg0;
        hipLaunchKernelGGL(k_out, dim3(B_ * 34), dim3(384), 0, stream,
                           ws, fin, outp);
    } else {
        hipLaunchKernelGGL(ldpc_decode_kernel, dim3(B_), dim3(1024), 0, stream,
                           xa, cw, vn, sh, outp, iters);
    }
}

// Round 8
// 206.065 us; speedup vs baseline: 1.0307x; 1.0307x over previous
//
#include <hip/hip_runtime.h>

// Boosted neural LDPC min-sum decoder, MI355X.
// R15: revert to R13 structure (best verified: 172.6us) + body-only trims.
//  Evidence R11~R12~R13-body, R14 regression: k_fit is NOT body-bound; the
//  ~8-10us/dispatch fixed cost (drain + cross-XCD L2 wb-inv + ramp) dominates,
//  and dispatch count is at its floor (10) for stream-legal launches.
//  Body trims this round: exact-dv gathers (no 8-pad dummies), nontemporal
//  msg stores (never re-read in-kernel), everything else R13-proven:
//  736 blocks x 384 (1 z/thread, 2 checks/block), scalar-uniform tables,
//  halo'd (2Z) planes, parallel table build, XCD-swizzled block maps.
// R10 lesson: persistent spin-barrier kernels deadlock under harness - banned.
// Sizes fixed by setup_inputs(): B=32, Z=384, N=68, M=46, dc=7, E=322, iters=8.
#define B_   32
#define Z_   384
#define N_   68
#define M_   46
#define DC_  7
#define E_   (M_ * DC_)      // 322
#define ZN   (Z_ * N_)       // 26112
#define ZM   (Z_ * M_)       // 17664
#define Z2   768             // halo'd plane length (2*Z)
#define MAXDV 20             // max variable degree supported (avg 4.7)

// halo'd message layout: [b][j][m][Z2] bytes + per-batch zero tail
#define PLZ(j,m) (((j) * M_ + (m)) * Z2)     // byte offset within batch
#define ZT    (DC_ * M_ * Z2)                // 247296 = zero-tail start (k_out dummies)
#define MS2S  (ZT + 1152)                    // per-batch msg bytes (div by 4)
// per-check gather table (ints):
//  [0..6]      llr base (vn*Z2 + s_j)      -> addr = xat2 + base + z
//  [7..13]     dv_j (exact)
//  [14+j*20+q] dv_j msg slot bases (byte offs, combined shift pre-added)
#define CST3  154
// per-variable out table: [0..7] recs (ZT dummies), [8]=dvx, [9..20] ext
#define OST   21

// ---- workspace layout (int32 offsets) ----
#define W2_XAT  0                            // float xat2[B][N][Z2]
#define XAT2I   (B_ * N_ * Z2)
#define MS2I    (B_ * MS2S / 4)
#define W2_MSG0 (W2_XAT + XAT2I)             // sbyte msg0[B][MS2S]
#define W2_MSG1 (W2_MSG0 + MS2I)             // sbyte msg1[B][MS2S]
#define W2_CHK  (W2_MSG1 + MS2I)             // int chk[M][CST3]
#define W2_OUT  (W2_CHK + M_ * CST3)         // int outt[N][OST]
#define W2_END  (W2_OUT + N_ * OST)          // ~5.65M ints ~= 22.6 MB

// msg[b][j][m][z(+Z)] = c2v message on edge j of check (m,z), sign applied, in
// half-steps, range [-15,15]. Exact ints -> fp arithmetic identical to JAX ref.

// ==================== k_pre: transpose(+halo) + PARALLEL tables ====================
// Blocks 0..191: xat2[b][n][z]=xat2[b][n][z+Z]=xa[b][z][n]; also zero a slice
// of both msg tails for batch b (k_out dummy target). Block 192: tables.
__global__ __launch_bounds__(384)
void k_pre(const float* __restrict__ xa,
           const int* __restrict__ vn_idx, const int* __restrict__ shifts,
           int* __restrict__ ws)
{
    const int tid = threadIdx.x;
    if (blockIdx.x == B_ * 6) {
        // ---- parallel table build (1 block); list order is arbitrary:
        //      sums of exact ints are order-free, so atomics are safe. ----
        __shared__ int vnl[E_], shl[E_], cntS[N_], posS[N_], offsS[N_ + 1], lstS[E_];
        if (tid < E_) { vnl[tid] = vn_idx[tid]; shl[tid] = shifts[tid]; }
        if (tid < N_) { cntS[tid] = 0; posS[tid] = 0; }
        __syncthreads();
        if (tid < E_) atomicAdd(&cntS[vnl[tid]], 1);
        __syncthreads();
        if (tid == 0) {
            offsS[0] = 0;
            for (int n = 0; n < N_; ++n) offsS[n + 1] = offsS[n] + cntS[n];
        }
        __syncthreads();
        if (tid < E_) {
            int m = tid / DC_, j = tid - m * DC_;
            int vn = vnl[tid];
            int r = atomicAdd(&posS[vn], 1);
            lstS[offsS[vn] + r] = (PLZ(j, m) << 9) | shl[tid];   // plane off | s'
        }
        __syncthreads();
        if (tid < E_) {             // per-check gather table (parallel per edge)
            int m = tid / DC_, j = tid - m * DC_;
            int vn = vnl[tid], sj = shl[tid];
            int* rec = ws + W2_CHK + m * CST3;
            rec[j] = vn * Z2 + sj;                        // llr base
            int o = offsS[vn];
            int dv = cntS[vn]; if (dv > MAXDV) dv = MAXDV;
            rec[7 + j] = dv;                              // exact count
            for (int q = 0; q < dv; ++q) {
                int lr = lstS[o + q];
                int sc = sj - (lr & 511); if (sc < 0) sc += Z_;  // combined shift
                rec[14 + j * 20 + q] = (lr >> 9) + sc;    // slot base (byte off)
            }
        }
        if (tid < N_) {             // per-variable out table (k_out, 8-padded)
            int* rr = ws + W2_OUT + tid * OST;
            int o = offsS[tid];
            int dv = cntS[tid]; if (dv > MAXDV) dv = MAXDV;
            rr[8] = (dv > 8) ? dv - 8 : 0;
            for (int q = 0; q < 8; ++q) {
                int slot = ZT;
                if (q < dv) { int lr = lstS[o + q]; slot = (lr >> 9) + (Z_ - (lr & 511)); }
                rr[q] = slot;                             // addr = base + z (halo'd)
            }
            for (int q = 8; q < dv; ++q) {
                int lr = lstS[o + q];
                rr[9 + (q - 8)] = (lr >> 9) + (Z_ - (lr & 511));
            }
        }
        return;
    }
    // ---- transpose: block = swizzled (b, 64-z tile); halo'd stores ----
    __shared__ float tile[N_ * 65];           // [n][zl], pad 65 breaks conflicts
    const int x = blockIdx.x & 7;
    const int k = blockIdx.x >> 3;            // 0..23
    const int b = x + 8 * (k & 3);            // b % 8 == x -> XCD locality
    const int t = k >> 2;                     // 0..5
    const int z0 = t * 64;
    const float* src = xa + (size_t)b * ZN + (size_t)z0 * N_;
    for (int i = tid; i < 64 * N_; i += 384) {  // contiguous 17 KB read
        int r = i / N_, n = i - r * N_;
        tile[n * 65 + r] = src[i];
    }
    // zero msg tails (k_out dummy target), slice t of batch b, both buffers
    {
        int* t0 = ws + W2_MSG0 + (b * MS2S + ZT) / 4;
        int* t1 = ws + W2_MSG1 + (b * MS2S + ZT) / 4;
        if (tid < 48) t0[t * 48 + tid] = 0;
        else if (tid < 96) t1[t * 48 + (tid - 48)] = 0;
    }
    __syncthreads();
    float* dst = (float*)(ws + W2_XAT) + (size_t)b * N_ * Z2;
    for (int i = tid; i < 64 * N_; i += 384) {
        int n = i >> 6, zl = i & 63;
        float v = tile[n * 65 + zl];
        dst[n * Z2 + z0 + zl] = v;            // main copy
        dst[n * Z2 + z0 + zl + Z_] = v;       // halo copy
    }
}

// ==================== k_fit: fused iteration (R13 structure) ====================
// Grid B_*23 = 736 blocks x 384 threads (2 checks/block, 1 z/thread).
// Thread = check (m, z) of batch b. Table reads wave-uniform -> scalar loads;
// gathers are byte loads with pre-added combined shifts (halo'd planes, no
// wrap math). Exact-dv loops (block-uniform dv -> no divergence). Msg stores
// nontemporal (never re-read in-kernel). INIT: v = clip(llr) only.
template <bool INIT>
__global__ __launch_bounds__(384)
void k_fit(const float* __restrict__ cw, const int* __restrict__ ws,
           const signed char* __restrict__ mold, signed char* __restrict__ mnew,
           int it)
{
    const int tid = threadIdx.x;
    const int bid = blockIdx.x;
    const int b = (bid & 7) + 8 * ((bid >> 3) & 3);   // b % 8 == bid % 8 (XCD)
    const int tile = bid >> 5;                // 0..22
    const int z = tid;                        // 384 threads == Z
    const float* xb = (const float*)(ws + W2_XAT) + (size_t)b * N_ * Z2;
    const signed char* mo = mold + (size_t)b * MS2S;
    signed char* mn = mnew + (size_t)b * MS2S;
    const float w = cw[it];

    #pragma unroll
    for (int s = 0; s < 2; ++s) {
        const int m = 2 * tile + s;
        const int* tb = ws + W2_CHK + m * CST3;       // uniform -> scalar loads
        float m1 = 1e30f, m2v = 1e30f;
        int f = 0, negb = 0;
        #pragma unroll
        for (int j = 0; j < DC_; ++j) {
            float v = xb[tb[j] + z];                  // llr_e (halo'd xat)
            if (!INIT) {
                const int dv = tb[7 + j];             // block-uniform
                int t2 = 0;                           // tot in exact half-steps
                for (int q = 0; q < dv; ++q)
                    t2 += (int)mo[tb[14 + j * 20 + q] + z];
                const int c2 = (int)mo[PLZ(j, m) + z];   // own old message
                // identical roundings to ref: fl(fl(llr + tot) - c2v)
                float lt = v + 0.5f * (float)t2;
                v = lt - 0.5f * (float)c2;
            }
            v = fminf(fmaxf(v, -20.0f), 20.0f);
            negb |= (v < 0.0f) << j;
            float a = fabsf(v);
            if (a < m1) { m2v = m1; m1 = a; f = j; }
            else if (a < m2v) { m2v = a; }
        }
        // quantize-STE forward: clip(rint(2*w*min)/2, +-7.5), as int half-steps
        float r1 = fminf(fmaxf(rintf(w * m1 * 2.0f), -15.0f), 15.0f);
        float r2 = fminf(fmaxf(rintf(w * m2v * 2.0f), -15.0f), 15.0f);
        const int q1 = (int)r1, q2 = (int)r2;
        const int par = __popc(negb);
        #pragma unroll
        for (int j = 0; j < DC_; ++j) {
            int q = (j == f) ? q2 : q1;
            int sj = (par - ((negb >> j) & 1)) & 1;   // parity of other edges
            signed char qv = (signed char)(sj ? -q : q);
            __builtin_nontemporal_store(qv, &mn[PLZ(j, m) + z]);        // main
            __builtin_nontemporal_store(qv, &mn[PLZ(j, m) + Z_ + z]);   // halo
        }
    }
}

// ==================== k_out: final variable totals ====================
// Grid 1088 blocks x 384 threads (2 variables/block).
__global__ __launch_bounds__(384)
void k_out(const int* __restrict__ ws, const signed char* __restrict__ msg,
           float* __restrict__ dst)
{
    const int tid = threadIdx.x;
    const int bid = blockIdx.x;
    const int b = (bid & 7) + 8 * ((bid >> 3) & 3);
    const int kk = bid >> 5;                  // 0..33
    const int z = tid;
    const signed char* mb = msg + (size_t)b * MS2S;
    const float* xb = (const float*)(ws + W2_XAT) + (size_t)b * N_ * Z2;
    #pragma unroll
    for (int s = 0; s < 2; ++s) {
        const int n = 2 * kk + s;
        const int* rr = ws + W2_OUT + n * OST;        // uniform -> scalar loads
        int t2 = 0;
        #pragma unroll
        for (int q = 0; q < 8; ++q)
            t2 += (int)mb[rr[q] + z];
        const int dvx = rr[8];
        for (int q = 0; q < dvx; ++q)
            t2 += (int)mb[rr[9 + q] + z];
        // fl(llr + tot); dst layout == out layout [b][n*Z+z]
        dst[(size_t)b * ZN + n * Z_ + z] = xb[n * Z2 + z] + 0.5f * (float)t2;
    }
}

// ==================== k_tr: iters==0 -> out = transpose(xa) ====================
__global__ __launch_bounds__(384)
void k_tr(const float* __restrict__ xa, float* __restrict__ dst_g)
{
    __shared__ float tile[N_ * 65];
    const int tid = threadIdx.x;
    const int x = blockIdx.x & 7;
    const int k = blockIdx.x >> 3;
    const int b = x + 8 * (k & 3);
    const int t = k >> 2;
    const int z0 = t * 64;
    const float* src = xa + (size_t)b * ZN + (size_t)z0 * N_;
    for (int i = tid; i < 64 * N_; i += 384) {
        int r = i / N_, n = i - r * N_;
        tile[n * 65 + r] = src[i];
    }
    __syncthreads();
    float* dst = dst_g + (size_t)b * ZN + z0;
    for (int i = tid; i < 64 * N_; i += 384) {
        int n = i >> 6, zl = i & 63;
        dst[n * Z_ + zl] = tile[n * 65 + zl];
    }
}

// ==================== fallback: single-block-per-batch kernel (small ws) ====================
#define INIT_STATE ((16u << 10) | (16u << 15))
__device__ __forceinline__ int decode2(unsigned st, int j) {
    int neg   = (st >> j) & 1;
    int q1    = (int)((st >> 10) & 31) - 16;
    int q2    = (int)((st >> 15) & 31) - 16;
    int first = (int)((st >> 7) & 7);
    int q     = (j == first) ? q2 : q1;
    int par   = (__popc(st & 127u) - neg) & 1;
    return par ? -q : q;
}

__global__ __launch_bounds__(1024)
void ldpc_decode_kernel(const float* __restrict__ xa,
                        const float* __restrict__ cw,
                        const int*   __restrict__ vn_idx,
                        const int*   __restrict__ shifts,
                        float* out, int iters)
{
    __shared__ short tot[ZN];
    __shared__ int   evs[E_];
    __shared__ int   offs[N_ + 1];
    __shared__ int   lists[E_];
    __shared__ float wlds[8];

    const int tid = threadIdx.x;
    const int b   = blockIdx.x;
    const float* xab = xa + (size_t)b * ZN;
    float* outb = out + (size_t)b * ZN;
    int* stateg = (int*)outb;

    if (tid < E_) evs[tid] = vn_idx[tid] | (shifts[tid] << 7);
    if (tid < iters && tid < 8) wlds[tid] = cw[tid];
    __syncthreads();
    if (tid < N_) {
        int c = 0;
        for (int e = 0; e < E_; ++e) c += ((evs[e] & 127) == tid);
        offs[tid + 1] = c;
    }
    if (tid == 0) offs[0] = 0;
    __syncthreads();
    if (tid == 0) { for (int n = 0; n < N_; ++n) offs[n + 1] += offs[n]; }
    __syncthreads();
    if (tid < N_) {
        int p = offs[tid];
        for (int e = 0; e < E_; ++e) {
            int rec = evs[e];
            if ((rec & 127) == tid) {
                int s = rec >> 7;
                lists[p++] = s | ((e / DC_) << 9) | ((e % DC_) << 15);
            }
        }
    }
    __syncthreads();

    for (int i = tid; i < ZM; i += 1024) stateg[i] = (int)INIT_STATE;
    __syncthreads();

    for (int it = 0; it < iters; ++it) {
        for (int i = tid; i < ZN; i += 1024) {
            int z = i / N_, n = i - z * N_, t2 = 0;
            int kend = offs[n + 1];
            for (int k = offs[n]; k < kend; ++k) {
                int rec = lists[k];
                int s = rec & 511, m = (rec >> 9) & 63, j = rec >> 15;
                int zs = z - s; if (zs < 0) zs += Z_;
                t2 += decode2((unsigned)stateg[zs * M_ + m], j);
            }
            tot[i] = (short)t2;
        }
        __syncthreads();
        const float w = wlds[it];
        for (int i = tid; i < ZM; i += 1024) {
            int z = i / M_, m = i - z * M_;
            unsigned st = (unsigned)stateg[i];
            float m1 = 1e30f, m2 = 1e30f;
            int f = 0, negb = 0;
            #pragma unroll
            for (int j = 0; j < DC_; ++j) {
                int rec = evs[m * DC_ + j];
                int vn = rec & 127, s = rec >> 7;
                int zr = z + s; if (zr >= Z_) zr -= Z_;
                int c2 = decode2(st, j);
                int idx = zr * N_ + vn;
                float v = (xab[idx] + 0.5f * (float)tot[idx]) - 0.5f * (float)c2;
                v = fminf(fmaxf(v, -20.0f), 20.0f);
                negb |= (v < 0.0f) << j;
                float a = fabsf(v);
                if (a < m1) { m2 = m1; m1 = a; f = j; }
                else if (a < m2) { m2 = a; }
            }
            float r1 = fminf(fmaxf(rintf(w * m1 * 2.0f), -15.0f), 15.0f);
            float r2 = fminf(fmaxf(rintf(w * m2 * 2.0f), -15.0f), 15.0f);
            stateg[i] = (int)(unsigned)(negb | (f << 7) | (((int)r1 + 16) << 10) | (((int)r2 + 16) << 15));
        }
        __syncthreads();
    }

    for (int i = tid; i < ZN; i += 1024) {
        int z = i / N_, n = i - z * N_, t2 = 0;
        int kend = offs[n + 1];
        for (int k = offs[n]; k < kend; ++k) {
            int rec = lists[k];
            int s = rec & 511, m = (rec >> 9) & 63, j = rec >> 15;
            int zs = z - s; if (zs < 0) zs += Z_;
            t2 += decode2((unsigned)stateg[zs * M_ + m], j);
        }
        tot[i] = (short)t2;
    }
    __syncthreads();
    for (int i = tid; i < ZN; i += 1024) {
        int n = i / Z_, z = i - n * Z_;
        outb[i] = xab[z * N_ + n] + 0.5f * (float)tot[z * N_ + n];
    }
}

extern "C" void kernel_launch(void* const* d_in, const int* in_sizes, int n_in,
                              void* d_out, int out_size, void* d_ws, size_t ws_size,
                              hipStream_t stream) {
    const float* xa = (const float*)d_in[0];
    const float* cw = (const float*)d_in[1];
    const int* vn   = (const int*)d_in[2];
    // d_in[3] = cn_idx: repeat(arange(M), dc) by construction — implicit.
    const int* sh   = (const int*)d_in[4];
    int iters = in_sizes[1];
    float* outp = (float*)d_out;

    if (ws_size >= (size_t)W2_END * sizeof(int)) {
        int*         ws   = (int*)d_ws;
        signed char* msg0 = (signed char*)(ws + W2_MSG0);
        signed char* msg1 = (signed char*)(ws + W2_MSG1);

        if (iters == 0) {   // out = transpose(xa)
            hipLaunchKernelGGL(k_tr, dim3(B_ * 6), dim3(384), 0, stream, xa, outp);
            return;
        }
        // transpose(+halo) + parallel tables + tail zeroing
        hipLaunchKernelGGL(k_pre, dim3(B_ * 6 + 1), dim3(384), 0, stream,
                           xa, vn, sh, ws);
        // it = 0: v = clip(llr) only, writes msg0
        hipLaunchKernelGGL((k_fit<true>), dim3(B_ * 23), dim3(384), 0, stream,
                           cw, ws, msg0, msg0, 0);
        // it = 1..iters-1: fused variable-total + check update, ping-pong
        for (int it = 1; it < iters; ++it) {
            signed char* wbuf = (it & 1) ? msg1 : msg0;
            signed char* rbuf = (it & 1) ? msg0 : msg1;
            hipLaunchKernelGGL((k_fit<false>), dim3(B_ * 23), dim3(384), 0, stream,
                               cw, ws, rbuf, wbuf, it);
        }
        signed char* fin = ((iters - 1) & 1) ? msg1 : msg0;
        hipLaunchKernelGGL(k_out, dim3(B_ * 34), dim3(384), 0, stream,
                           ws, fin, outp);
    } else {
        hipLaunchKernelGGL(ldpc_decode_kernel, dim3(B_), dim3(1024), 0, stream,
                           xa, cw, vn, sh, outp, iters);
    }
}

// Round 9
// 183.125 us; speedup vs baseline: 1.1598x; 1.1253x over previous
//
#include <hip/hip_runtime.h>

// Boosted neural LDPC min-sum decoder, MI355X.
// R16: exact R13 structure (best verified: 172.6us) + msg-halo removal ONLY.
//  - R15 lesson: exact-dv runtime gather loops serialize (R11 redux) and NT
//    byte stores bypass L2 -> both reverted. Padded-8 compile-time gather
//    loops + plain stores restored.
//  - New: msg planes are single-copy (length Z, not 2Z). Gather wrap handled
//    by per-slot scalar threshold: a=base+z; if(a>=thr) a-=Z (2 VALU/gather).
//    Cuts msg stores 14->7 per check-thread and msg footprint 15.8->8 MB =
//    half the dirty-L2 writeback on the inter-dispatch critical path.
//  - Kept: parallel table build, halo'd xat (read-only), scalar-uniform
//    tables, 736x384 fit grid (2 checks/block), XCD-swizzled block maps.
// R10 lesson: persistent spin-barrier kernels deadlock under harness - banned.
// Sizes fixed by setup_inputs(): B=32, Z=384, N=68, M=46, dc=7, E=322, iters=8.
#define B_   32
#define Z_   384
#define N_   68
#define M_   46
#define DC_  7
#define E_   (M_ * DC_)      // 322
#define ZN   (Z_ * N_)       // 26112
#define ZM   (Z_ * M_)       // 17664
#define Z2   768             // halo'd xat plane length (2*Z)
#define MAXDV 20             // max variable degree supported (avg 4.7)

// single-copy message layout: [b][j][m][Z_] bytes + per-batch zero tail
#define PLB(j,m) (((j) * M_ + (m)) * Z_)     // byte offset within batch
#define ZT    (DC_ * M_ * Z_)                // 123648 = zero-tail start (dummies)
#define MS2S  (ZT + 1152)                    // 124800 bytes per batch (div 4)
// per-check gather table (ints), all reads wave-uniform:
//  [0..6]        llr base (vn*Z2 + s_j)   -> addr = xat2 + base + z (xat halo'd)
//  [7..13]       dvx_j = max(dv-8, 0)
//  [14+j*8+q]    slot base q (byte off, combined shift pre-added; dummy -> ZT)
//  [70+j*8+q]    slot thr q  (plane+Z; dummy -> INT_MAX)   a>=thr ? a-Z : a
//  [126+j*12+q]  ext slot base (dv in (8..MAXDV])
//  [210+j*12+q]  ext slot thr
#define CST4  294
// per-variable out table: [0..7] base, [8..15] thr, [16]=dvx,
//  [17..28] ext base, [29..40] ext thr
#define OST4  41

// ---- workspace layout (int32 offsets) ----
#define W2_XAT  0                            // float xat2[B][N][Z2]
#define XAT2I   (B_ * N_ * Z2)
#define MS2I    (B_ * MS2S / 4)
#define W2_MSG0 (W2_XAT + XAT2I)             // sbyte msg0[B][MS2S]
#define W2_MSG1 (W2_MSG0 + MS2I)             // sbyte msg1[B][MS2S]
#define W2_CHK  (W2_MSG1 + MS2I)             // int chk[M][CST4]
#define W2_OUT  (W2_CHK + M_ * CST4)         // int outt[N][OST4]
#define W2_END  (W2_OUT + N_ * OST4)         // ~3.7M ints ~= 14.7 MB

// msg[b][j][m][z] = c2v message on edge j of check (m,z), sign applied, in
// half-steps, range [-15,15]. Exact ints -> fp arithmetic identical to JAX ref.

// ==================== k_pre: transpose(+xat halo) + PARALLEL tables ====================
// Blocks 0..191: xat2[b][n][z]=xat2[b][n][z+Z]=xa[b][z][n]; also zero a slice
// of both msg tails for batch b (dummy-slot target). Block 192: tables.
__global__ __launch_bounds__(384)
void k_pre(const float* __restrict__ xa,
           const int* __restrict__ vn_idx, const int* __restrict__ shifts,
           int* __restrict__ ws)
{
    const int tid = threadIdx.x;
    if (blockIdx.x == B_ * 6) {
        // ---- parallel table build (1 block); list order is arbitrary:
        //      sums of exact ints are order-free, so atomics are safe. ----
        __shared__ int vnl[E_], shl[E_], cntS[N_], posS[N_], offsS[N_ + 1], lstS[E_];
        if (tid < E_) { vnl[tid] = vn_idx[tid]; shl[tid] = shifts[tid]; }
        if (tid < N_) { cntS[tid] = 0; posS[tid] = 0; }
        __syncthreads();
        if (tid < E_) atomicAdd(&cntS[vnl[tid]], 1);
        __syncthreads();
        if (tid == 0) {
            offsS[0] = 0;
            for (int n = 0; n < N_; ++n) offsS[n + 1] = offsS[n] + cntS[n];
        }
        __syncthreads();
        if (tid < E_) {
            int m = tid / DC_, j = tid - m * DC_;
            int vn = vnl[tid];
            int r = atomicAdd(&posS[vn], 1);
            lstS[offsS[vn] + r] = (PLB(j, m) << 9) | shl[tid];   // plane off | s'
        }
        __syncthreads();
        if (tid < E_) {             // per-check gather table (parallel per edge)
            int m = tid / DC_, j = tid - m * DC_;
            int vn = vnl[tid], sj = shl[tid];
            int* rec = ws + W2_CHK + m * CST4;
            rec[j] = vn * Z2 + sj;                        // llr base (xat halo'd)
            int o = offsS[vn];
            int dv = cntS[vn]; if (dv > MAXDV) dv = MAXDV;
            rec[7 + j] = (dv > 8) ? dv - 8 : 0;
            for (int q = 0; q < 8; ++q) {
                int sb = ZT, st = 0x7fffffff;             // dummy -> zero tail
                if (q < dv) {
                    int lr = lstS[o + q];
                    int pl = lr >> 9, sp = lr & 511;
                    int sc = sj - sp; if (sc < 0) sc += Z_;  // combined shift
                    sb = pl + sc; st = pl + Z_;
                }
                rec[14 + j * 8 + q] = sb;
                rec[70 + j * 8 + q] = st;
            }
            for (int q = 8; q < dv; ++q) {
                int lr = lstS[o + q];
                int pl = lr >> 9, sp = lr & 511;
                int sc = sj - sp; if (sc < 0) sc += Z_;
                rec[126 + j * 12 + (q - 8)] = pl + sc;
                rec[210 + j * 12 + (q - 8)] = pl + Z_;
            }
        }
        if (tid < N_) {             // per-variable out table (8-padded)
            int* rr = ws + W2_OUT + tid * OST4;
            int o = offsS[tid];
            int dv = cntS[tid]; if (dv > MAXDV) dv = MAXDV;
            rr[16] = (dv > 8) ? dv - 8 : 0;
            for (int q = 0; q < 8; ++q) {
                int sb = ZT, st = 0x7fffffff;
                if (q < dv) {
                    int lr = lstS[o + q];
                    int pl = lr >> 9, sp = lr & 511;
                    sb = pl + (Z_ - sp); st = pl + Z_;    // (z - s') mod Z
                }
                rr[q] = sb;
                rr[8 + q] = st;
            }
            for (int q = 8; q < dv; ++q) {
                int lr = lstS[o + q];
                int pl = lr >> 9, sp = lr & 511;
                rr[17 + (q - 8)] = pl + (Z_ - sp);
                rr[29 + (q - 8)] = pl + Z_;
            }
        }
        return;
    }
    // ---- transpose: block = swizzled (b, 64-z tile); halo'd xat stores ----
    __shared__ float tile[N_ * 65];           // [n][zl], pad 65 breaks conflicts
    const int x = blockIdx.x & 7;
    const int k = blockIdx.x >> 3;            // 0..23
    const int b = x + 8 * (k & 3);            // b % 8 == x -> XCD locality
    const int t = k >> 2;                     // 0..5
    const int z0 = t * 64;
    const float* src = xa + (size_t)b * ZN + (size_t)z0 * N_;
    for (int i = tid; i < 64 * N_; i += 384) {  // contiguous 17 KB read
        int r = i / N_, n = i - r * N_;
        tile[n * 65 + r] = src[i];
    }
    // zero msg tails (dummy-slot target), slice t of batch b, both buffers
    {
        int* t0 = ws + W2_MSG0 + (b * MS2S + ZT) / 4;
        int* t1 = ws + W2_MSG1 + (b * MS2S + ZT) / 4;
        if (tid < 48) t0[t * 48 + tid] = 0;
        else if (tid < 96) t1[t * 48 + (tid - 48)] = 0;
    }
    __syncthreads();
    float* dst = (float*)(ws + W2_XAT) + (size_t)b * N_ * Z2;
    for (int i = tid; i < 64 * N_; i += 384) {
        int n = i >> 6, zl = i & 63;
        float v = tile[n * 65 + zl];
        dst[n * Z2 + z0 + zl] = v;            // main copy
        dst[n * Z2 + z0 + zl + Z_] = v;       // halo copy
    }
}

// ==================== k_fit: fused iteration (R13 structure) ====================
// Grid B_*23 = 736 blocks x 384 threads (2 checks/block, 1 z/thread).
// Thread = check (m, z) of batch b. Table reads wave-uniform -> scalar loads;
// gathers: a = base + z, wrapped by scalar threshold (single-copy planes).
// Padded-8 compile-time loops; dummies read the zero tail. INIT: clip(llr).
template <bool INIT>
__global__ __launch_bounds__(384)
void k_fit(const float* __restrict__ cw, const int* __restrict__ ws,
           const signed char* __restrict__ mold, signed char* __restrict__ mnew,
           int it)
{
    const int tid = threadIdx.x;
    const int bid = blockIdx.x;
    const int b = (bid & 7) + 8 * ((bid >> 3) & 3);   // b % 8 == bid % 8 (XCD)
    const int tile = bid >> 5;                // 0..22
    const int z = tid;                        // 384 threads == Z
    const float* xb = (const float*)(ws + W2_XAT) + (size_t)b * N_ * Z2;
    const signed char* mo = mold + (size_t)b * MS2S;
    signed char* mn = mnew + (size_t)b * MS2S;
    const float w = cw[it];

    #pragma unroll
    for (int s = 0; s < 2; ++s) {
        const int m = 2 * tile + s;
        const int* tb = ws + W2_CHK + m * CST4;       // uniform -> scalar loads
        float m1 = 1e30f, m2v = 1e30f;
        int f = 0, negb = 0;
        #pragma unroll
        for (int j = 0; j < DC_; ++j) {
            float v = xb[tb[j] + z];                  // llr_e (halo'd xat)
            if (!INIT) {
                int t2 = 0;                           // tot in exact half-steps
                #pragma unroll
                for (int q = 0; q < 8; ++q) {         // batch-issued, thr-wrapped
                    int a = tb[14 + j * 8 + q] + z;
                    if (a >= tb[70 + j * 8 + q]) a -= Z_;
                    t2 += (int)mo[a];
                }
                const int dvx = tb[7 + j];            // uniform, usually 0
                for (int q = 0; q < dvx; ++q) {
                    int a = tb[126 + j * 12 + q] + z;
                    if (a >= tb[210 + j * 12 + q]) a -= Z_;
                    t2 += (int)mo[a];
                }
                const int c2 = (int)mo[PLB(j, m) + z];   // own old message
                // identical roundings to ref: fl(fl(llr + tot) - c2v)
                float lt = v + 0.5f * (float)t2;
                v = lt - 0.5f * (float)c2;
            }
            v = fminf(fmaxf(v, -20.0f), 20.0f);
            negb |= (v < 0.0f) << j;
            float a = fabsf(v);
            if (a < m1) { m2v = m1; m1 = a; f = j; }
            else if (a < m2v) { m2v = a; }
        }
        // quantize-STE forward: clip(rint(2*w*min)/2, +-7.5), as int half-steps
        float r1 = fminf(fmaxf(rintf(w * m1 * 2.0f), -15.0f), 15.0f);
        float r2 = fminf(fmaxf(rintf(w * m2v * 2.0f), -15.0f), 15.0f);
        const int q1 = (int)r1, q2 = (int)r2;
        const int par = __popc(negb);
        #pragma unroll
        for (int j = 0; j < DC_; ++j) {
            int q = (j == f) ? q2 : q1;
            int sj = (par - ((negb >> j) & 1)) & 1;   // parity of other edges
            mn[PLB(j, m) + z] = (signed char)(sj ? -q : q);   // single copy
        }
    }
}

// ==================== k_out: final variable totals ====================
// Grid 1088 blocks x 384 threads (2 variables/block).
__global__ __launch_bounds__(384)
void k_out(const int* __restrict__ ws, const signed char* __restrict__ msg,
           float* __restrict__ dst)
{
    const int tid = threadIdx.x;
    const int bid = blockIdx.x;
    const int b = (bid & 7) + 8 * ((bid >> 3) & 3);
    const int kk = bid >> 5;                  // 0..33
    const int z = tid;
    const signed char* mb = msg + (size_t)b * MS2S;
    const float* xb = (const float*)(ws + W2_XAT) + (size_t)b * N_ * Z2;
    #pragma unroll
    for (int s = 0; s < 2; ++s) {
        const int n = 2 * kk + s;
        const int* rr = ws + W2_OUT + n * OST4;       // uniform -> scalar loads
        int t2 = 0;
        #pragma unroll
        for (int q = 0; q < 8; ++q) {
            int a = rr[q] + z;
            if (a >= rr[8 + q]) a -= Z_;
            t2 += (int)mb[a];
        }
        const int dvx = rr[16];
        for (int q = 0; q < dvx; ++q) {
            int a = rr[17 + q] + z;
            if (a >= rr[29 + q]) a -= Z_;
            t2 += (int)mb[a];
        }
        // fl(llr + tot); dst layout == out layout [b][n*Z+z]
        dst[(size_t)b * ZN + n * Z_ + z] = xb[n * Z2 + z] + 0.5f * (float)t2;
    }
}

// ==================== k_tr: iters==0 -> out = transpose(xa) ====================
__global__ __launch_bounds__(384)
void k_tr(const float* __restrict__ xa, float* __restrict__ dst_g)
{
    __shared__ float tile[N_ * 65];
    const int tid = threadIdx.x;
    const int x = blockIdx.x & 7;
    const int k = blockIdx.x >> 3;
    const int b = x + 8 * (k & 3);
    const int t = k >> 2;
    const int z0 = t * 64;
    const float* src = xa + (size_t)b * ZN + (size_t)z0 * N_;
    for (int i = tid; i < 64 * N_; i += 384) {
        int r = i / N_, n = i - r * N_;
        tile[n * 65 + r] = src[i];
    }
    __syncthreads();
    float* dst = dst_g + (size_t)b * ZN + z0;
    for (int i = tid; i < 64 * N_; i += 384) {
        int n = i >> 6, zl = i & 63;
        dst[n * Z_ + zl] = tile[n * 65 + zl];
    }
}

// ==================== fallback: single-block-per-batch kernel (small ws) ====================
#define INIT_STATE ((16u << 10) | (16u << 15))
__device__ __forceinline__ int decode2(unsigned st, int j) {
    int neg   = (st >> j) & 1;
    int q1    = (int)((st >> 10) & 31) - 16;
    int q2    = (int)((st >> 15) & 31) - 16;
    int first = (int)((st >> 7) & 7);
    int q     = (j == first) ? q2 : q1;
    int par   = (__popc(st & 127u) - neg) & 1;
    return par ? -q : q;
}

__global__ __launch_bounds__(1024)
void ldpc_decode_kernel(const float* __restrict__ xa,
                        const float* __restrict__ cw,
                        const int*   __restrict__ vn_idx,
                        const int*   __restrict__ shifts,
                        float* out, int iters)
{
    __shared__ short tot[ZN];
    __shared__ int   evs[E_];
    __shared__ int   offs[N_ + 1];
    __shared__ int   lists[E_];
    __shared__ float wlds[8];

    const int tid = threadIdx.x;
    const int b   = blockIdx.x;
    const float* xab = xa + (size_t)b * ZN;
    float* outb = out + (size_t)b * ZN;
    int* stateg = (int*)outb;

    if (tid < E_) evs[tid] = vn_idx[tid] | (shifts[tid] << 7);
    if (tid < iters && tid < 8) wlds[tid] = cw[tid];
    __syncthreads();
    if (tid < N_) {
        int c = 0;
        for (int e = 0; e < E_; ++e) c += ((evs[e] & 127) == tid);
        offs[tid + 1] = c;
    }
    if (tid == 0) offs[0] = 0;
    __syncthreads();
    if (tid == 0) { for (int n = 0; n < N_; ++n) offs[n + 1] += offs[n]; }
    __syncthreads();
    if (tid < N_) {
        int p = offs[tid];
        for (int e = 0; e < E_; ++e) {
            int rec = evs[e];
            if ((rec & 127) == tid) {
                int s = rec >> 7;
                lists[p++] = s | ((e / DC_) << 9) | ((e % DC_) << 15);
            }
        }
    }
    __syncthreads();

    for (int i = tid; i < ZM; i += 1024) stateg[i] = (int)INIT_STATE;
    __syncthreads();

    for (int it = 0; it < iters; ++it) {
        for (int i = tid; i < ZN; i += 1024) {
            int z = i / N_, n = i - z * N_, t2 = 0;
            int kend = offs[n + 1];
            for (int k = offs[n]; k < kend; ++k) {
                int rec = lists[k];
                int s = rec & 511, m = (rec >> 9) & 63, j = rec >> 15;
                int zs = z - s; if (zs < 0) zs += Z_;
                t2 += decode2((unsigned)stateg[zs * M_ + m], j);
            }
            tot[i] = (short)t2;
        }
        __syncthreads();
        const float w = wlds[it];
        for (int i = tid; i < ZM; i += 1024) {
            int z = i / M_, m = i - z * M_;
            unsigned st = (unsigned)stateg[i];
            float m1 = 1e30f, m2 = 1e30f;
            int f = 0, negb = 0;
            #pragma unroll
            for (int j = 0; j < DC_; ++j) {
                int rec = evs[m * DC_ + j];
                int vn = rec & 127, s = rec >> 7;
                int zr = z + s; if (zr >= Z_) zr -= Z_;
                int c2 = decode2(st, j);
                int idx = zr * N_ + vn;
                float v = (xab[idx] + 0.5f * (float)tot[idx]) - 0.5f * (float)c2;
                v = fminf(fmaxf(v, -20.0f), 20.0f);
                negb |= (v < 0.0f) << j;
                float a = fabsf(v);
                if (a < m1) { m2 = m1; m1 = a; f = j; }
                else if (a < m2) { m2 = a; }
            }
            float r1 = fminf(fmaxf(rintf(w * m1 * 2.0f), -15.0f), 15.0f);
            float r2 = fminf(fmaxf(rintf(w * m2 * 2.0f), -15.0f), 15.0f);
            stateg[i] = (int)(unsigned)(negb | (f << 7) | (((int)r1 + 16) << 10) | (((int)r2 + 16) << 15));
        }
        __syncthreads();
    }

    for (int i = tid; i < ZN; i += 1024) {
        int z = i / N_, n = i - z * N_, t2 = 0;
        int kend = offs[n + 1];
        for (int k = offs[n]; k < kend; ++k) {
            int rec = lists[k];
            int s = rec & 511, m = (rec >> 9) & 63, j = rec >> 15;
            int zs = z - s; if (zs < 0) zs += Z_;
            t2 += decode2((unsigned)stateg[zs * M_ + m], j);
        }
        tot[i] = (short)t2;
    }
    __syncthreads();
    for (int i = tid; i < ZN; i += 1024) {
        int n = i / Z_, z = i - n * Z_;
        outb[i] = xab[z * N_ + n] + 0.5f * (float)tot[z * N_ + n];
    }
}

extern "C" void kernel_launch(void* const* d_in, const int* in_sizes, int n_in,
                              void* d_out, int out_size, void* d_ws, size_t ws_size,
                              hipStream_t stream) {
    const float* xa = (const float*)d_in[0];
    const float* cw = (const float*)d_in[1];
    const int* vn   = (const int*)d_in[2];
    // d_in[3] = cn_idx: repeat(arange(M), dc) by construction — implicit.
    const int* sh   = (const int*)d_in[4];
    int iters = in_sizes[1];
    float* outp = (float*)d_out;

    if (ws_size >= (size_t)W2_END * sizeof(int)) {
        int*         ws   = (int*)d_ws;
        signed char* msg0 = (signed char*)(ws + W2_MSG0);
        signed char* msg1 = (signed char*)(ws + W2_MSG1);

        if (iters == 0) {   // out = transpose(xa)
            hipLaunchKernelGGL(k_tr, dim3(B_ * 6), dim3(384), 0, stream, xa, outp);
            return;
        }
        // transpose(+xat halo) + parallel tables + tail zeroing
        hipLaunchKernelGGL(k_pre, dim3(B_ * 6 + 1), dim3(384), 0, stream,
                           xa, vn, sh, ws);
        // it = 0: v = clip(llr) only, writes msg0
        hipLaunchKernelGGL((k_fit<true>), dim3(B_ * 23), dim3(384), 0, stream,
                           cw, ws, msg0, msg0, 0);
        // it = 1..iters-1: fused variable-total + check update, ping-pong
        for (int it = 1; it < iters; ++it) {
            signed char* wbuf = (it & 1) ? msg1 : msg0;
            signed char* rbuf = (it & 1) ? msg0 : msg1;
            hipLaunchKernelGGL((k_fit<false>), dim3(B_ * 23), dim3(384), 0, stream,
                               cw, ws, rbuf, wbuf, it);
        }
        signed char* fin = ((iters - 1) & 1) ? msg1 : msg0;
        hipLaunchKernelGGL(k_out, dim3(B_ * 34), dim3(384), 0, stream,
                           ws, fin, outp);
    } else {
        hipLaunchKernelGGL(ldpc_decode_kernel, dim3(B_), dim3(1024), 0, stream,
                           xa, cw, vn, sh, outp, iters);
    }
}